// Round 2
// baseline (186.036 us; speedup 1.0000x reference)
//
#include <hip/hip_runtime.h>
#include <math.h>

#define TILE 64
#define HALO 9                   // 8 (gauss radius) + 1 (sobel radius)
#define REG  (TILE + 2*HALO)     // 82: mean region rows/cols
#define REGS 84                  // padded LDS stride for mean / tmpH
#define BR   (TILE + 2)          // 66: blur rows/cols (sobel needs +-1 ring)
#define BRS  68                  // padded LDS stride for blur
#define IMG  512

__device__ __forceinline__ int reflect_idx(int i) {
    // numpy 'symmetric' / scipy 'reflect': -1 -> 0, -2 -> 1, ..., N -> N-1
    if (i < 0) i = -i - 1;
    if (i >= IMG) i = 2 * IMG - 1 - i;
    return i;
}

__global__ __launch_bounds__(256) void sobel_fused(
    const float* __restrict__ x, float* __restrict__ out)
{
    __shared__ float sA[REG * REGS];   // phase1: mean region; phase3+: blur (aliased)
    __shared__ float sB[BR * REGS];    // phase2: H-blurred rows

    const int t  = threadIdx.x;
    const int w0 = blockIdx.x * TILE;
    const int h0 = blockIdx.y * TILE;
    const int b  = blockIdx.z;

    // 17-tap gaussian weights (sigma=2), computed in f32 like numpy
    float gw[17];
    {
        float s = 0.f;
        #pragma unroll
        for (int i = 0; i < 17; ++i) {
            float xx = (float)(i - 8);
            gw[i] = expf(-0.125f * xx * xx);
            s += gw[i];
        }
        float inv = 1.0f / s;
        #pragma unroll
        for (int i = 0; i < 17; ++i) gw[i] *= inv;
    }

    // ---- phase 1: channel mean into LDS (with symmetric reflect at edges) ----
    const float* xb = x + (size_t)b * 3 * IMG * IMG;
    const float third = 1.0f / 3.0f;
    for (int idx = t; idx < REG * REG; idx += 256) {
        int r = idx / REG, c = idx - r * REG;
        int gr = reflect_idx(h0 - HALO + r);
        int gc = reflect_idx(w0 - HALO + c);
        const float* p = xb + gr * IMG + gc;
        sA[r * REGS + c] = (p[0] + p[IMG * IMG] + p[2 * IMG * IMG]) * third;
    }
    __syncthreads();

    // ---- phase 2: gaussian blur along H: rows [h0-1, h0+65), all 82 cols ----
    for (int idx = t; idx < BR * REG; idx += 256) {
        int r = idx / REG, c = idx - r * REG;
        float acc = 0.f;
        #pragma unroll
        for (int k = 0; k < 17; ++k) acc += gw[k] * sA[(r + k) * REGS + c];
        sB[r * REGS + c] = acc;
    }
    __syncthreads();

    // ---- phase 3: gaussian blur along W into sBlur (= sA, mean is dead) ----
    // zero out-of-image ring: sobel uses zero padding on the blurred image
    float* sBlur = sA;
    for (int idx = t; idx < BR * BR; idx += 256) {
        int r = idx / BR, c = idx - r * BR;
        float acc = 0.f;
        #pragma unroll
        for (int k = 0; k < 17; ++k) acc += gw[k] * sB[r * REGS + c + k];
        int gr = h0 - 1 + r, gc = w0 - 1 + c;
        bool in = (gr >= 0) & (gr < IMG) & (gc >= 0) & (gc < IMG);
        sBlur[r * BRS + c] = in ? acc : 0.f;
    }
    __syncthreads();

    // ---- phase 4: sobel + hypot, write out ----
    for (int idx = t; idx < TILE * TILE; idx += 256) {
        int r = idx >> 6, c = idx & 63;
        const float* bp = sBlur + r * BRS + c;   // top-left of 3x3 at (r-1,c-1) rel. center
        float tl = bp[0],       tm = bp[1],       tr = bp[2];
        float ml = bp[BRS],                        mr = bp[BRS + 2];
        float bl = bp[2 * BRS], bm = bp[2 * BRS + 1], br2 = bp[2 * BRS + 2];
        // sx: deriv along H ([-1,0,1]), smooth along W ([1,2,1])
        float sx = (bl - tl) + 2.f * (bm - tm) + (br2 - tr);
        // sy: deriv along W, smooth along H
        float sy = (tr - tl) + 2.f * (mr - ml) + (br2 - bl);
        out[((size_t)b * IMG + (h0 + r)) * IMG + (w0 + c)] = sqrtf(sx * sx + sy * sy);
    }
}

extern "C" void kernel_launch(void* const* d_in, const int* in_sizes, int n_in,
                              void* d_out, int out_size, void* d_ws, size_t ws_size,
                              hipStream_t stream) {
    const float* x = (const float*)d_in[0];
    float* out = (float*)d_out;
    dim3 grid(IMG / TILE, IMG / TILE, 32);   // 8 x 8 x 32
    dim3 block(256);
    hipLaunchKernelGGL(sobel_fused, grid, block, 0, stream, x, out);
}